// Round 1
// baseline (371.743 us; speedup 1.0000x reference)
//
#include <hip/hip_runtime.h>

// DeepFM: B=16384, D=1024, L=4
//   inter = relu(x * rowsum(x));  h = x; 4x h = relu(h @ W[i]^T + b[i]);
//   out = ((h + inter)*0.5) @ Wo^T + bo
// Strategy: bf16 MFMA GEMM chain (m97 structure: 128x128 tile, BK=32,
// global_load_lds width=16, 16x16x32 bf16 MFMA, fp32 accum).

#define DDIM 1024
#define BROWS 16384
#define NLAYERS 4

typedef __attribute__((ext_vector_type(8))) short s8v;   // 8 bf16 (4 VGPRs)
typedef __attribute__((ext_vector_type(4))) float f4v;   // 4 fp32 acc

__device__ __forceinline__ unsigned short f2bf(float f) {
    unsigned int u = __float_as_uint(f);
    u += 0x7fffu + ((u >> 16) & 1u);   // round-to-nearest-even
    return (unsigned short)(u >> 16);
}

__device__ __forceinline__ void gld16(const void* g, void* l) {
    __builtin_amdgcn_global_load_lds(
        (const __attribute__((address_space(1))) unsigned int*)g,
        (__attribute__((address_space(3))) unsigned int*)l, 16, 0, 0);
}

// ---------------- prep: x fp32 -> bf16, rowsum(x) fp32 -------------------
__global__ __launch_bounds__(256) void prep_kernel(
    const float* __restrict__ x, unsigned short* __restrict__ xb,
    float* __restrict__ rowsum)
{
    const int row = blockIdx.x;
    const int t = threadIdx.x;
    const float4 v = *(const float4*)(x + (size_t)row * DDIM + t * 4);
    ushort4 o;
    o.x = f2bf(v.x); o.y = f2bf(v.y); o.z = f2bf(v.z); o.w = f2bf(v.w);
    *(ushort4*)(xb + (size_t)row * DDIM + t * 4) = o;
    float s = v.x + v.y + v.z + v.w;
    #pragma unroll
    for (int off = 32; off > 0; off >>= 1) s += __shfl_down(s, off, 64);
    __shared__ float red[4];
    const int wave = t >> 6, lane = t & 63;
    if (lane == 0) red[wave] = s;
    __syncthreads();
    if (t == 0) rowsum[row] = red[0] + red[1] + red[2] + red[3];
}

// ---------------- convert fp32 -> bf16 (weights) -------------------------
__global__ __launch_bounds__(256) void cvt_kernel(
    const float* __restrict__ in, unsigned short* __restrict__ out, int n)
{
    const int i = (blockIdx.x * 256 + threadIdx.x) * 4;
    if (i < n) {
        const float4 v = *(const float4*)(in + i);
        ushort4 o;
        o.x = f2bf(v.x); o.y = f2bf(v.y); o.z = f2bf(v.z); o.w = f2bf(v.w);
        *(ushort4*)(out + i) = o;
    }
}

// ---------------- GEMM: C = A(MxK) @ Bw(NxK)^T + bias --------------------
// MODE 0: out bf16 = relu(z)
// MODE 1: out bf16 = 0.5*(relu(z) + relu(x*rowsum))   (layer 4 fusion)
// MODE 2: out fp32 = z                                 (final layer)
template <int MODE>
__global__ __launch_bounds__(256, 2) void gemm_bt(
    const unsigned short* __restrict__ A,
    const unsigned short* __restrict__ Bw,
    const float* __restrict__ bias,
    void* __restrict__ out,
    const float* __restrict__ xf,
    const float* __restrict__ rowsum,
    int M, int N, int K)
{
    constexpr int BM = 128, BN = 128, BK = 32;
    __shared__ unsigned short sA[BM * BK];   // [m][k] row-major, 8 KB
    __shared__ unsigned short sB[BN * BK];   // [n][k] row-major, 8 KB

    const int t = threadIdx.x;
    const int wave = t >> 6, lane = t & 63;
    const int wm = wave & 1, wn = wave >> 1;       // 2x2 wave grid of 64x64
    const int rowBase = blockIdx.x * BM;
    const int colBase = blockIdx.y * BN;

    f4v acc[4][4] = {};

    const int c0r = t >> 2,         c0k = (t & 3) * 8;
    const int c1r = (t + 256) >> 2, c1k = ((t + 256) & 3) * 8;

    for (int kt = 0; kt < K; kt += BK) {
        if (kt) __syncthreads();
        gld16(A  + (size_t)(rowBase + c0r) * K + kt + c0k, (char*)sA + t * 16);
        gld16(Bw + (size_t)(colBase + c0r) * K + kt + c0k, (char*)sB + t * 16);
        gld16(A  + (size_t)(rowBase + c1r) * K + kt + c1k, (char*)sA + (t + 256) * 16);
        gld16(Bw + (size_t)(colBase + c1r) * K + kt + c1k, (char*)sB + (t + 256) * 16);
        __syncthreads();

        const int mrow = lane & 15;
        const int koff = (lane >> 4) * 8;
        s8v af[4], bfr[4];
        #pragma unroll
        for (int mi = 0; mi < 4; ++mi)
            af[mi] = *(const s8v*)&sA[(wm * 64 + mi * 16 + mrow) * BK + koff];
        #pragma unroll
        for (int ni = 0; ni < 4; ++ni)
            bfr[ni] = *(const s8v*)&sB[(wn * 64 + ni * 16 + mrow) * BK + koff];
        #pragma unroll
        for (int mi = 0; mi < 4; ++mi)
            #pragma unroll
            for (int ni = 0; ni < 4; ++ni)
                acc[mi][ni] = __builtin_amdgcn_mfma_f32_16x16x32_bf16(
                    af[mi], bfr[ni], acc[mi][ni], 0, 0, 0);
    }

    // Epilogue. C/D layout: col = lane&15, row = (lane>>4)*4 + reg  (m89/m91)
    const int nlane = lane & 15;
    const int rbase = (lane >> 4) * 4;
    #pragma unroll
    for (int ni = 0; ni < 4; ++ni) {
        const int n = colBase + wn * 64 + ni * 16 + nlane;
        const float bv = bias[n];
        #pragma unroll
        for (int mi = 0; mi < 4; ++mi) {
            const int mbase = rowBase + wm * 64 + mi * 16 + rbase;
            #pragma unroll
            for (int r = 0; r < 4; ++r) {
                const int row = mbase + r;
                float v = acc[mi][ni][r] + bv;
                if (MODE == 0) {
                    v = v > 0.f ? v : 0.f;
                    ((unsigned short*)out)[(size_t)row * N + n] = f2bf(v);
                } else if (MODE == 1) {
                    v = v > 0.f ? v : 0.f;
                    float it = xf[(size_t)row * N + n] * rowsum[row];
                    it = it > 0.f ? it : 0.f;
                    ((unsigned short*)out)[(size_t)row * N + n] = f2bf(0.5f * (v + it));
                } else {
                    ((float*)out)[(size_t)row * N + n] = v;
                }
            }
        }
    }
}

extern "C" void kernel_launch(void* const* d_in, const int* in_sizes, int n_in,
                              void* d_out, int out_size, void* d_ws, size_t ws_size,
                              hipStream_t stream) {
    const float* x  = (const float*)d_in[0];
    const float* Ws = (const float*)d_in[1];
    const float* bs = (const float*)d_in[2];
    const float* Wo = (const float*)d_in[3];
    const float* bo = (const float*)d_in[4];
    float* out = (float*)d_out;

    char* ws = (char*)d_ws;
    // workspace layout (bytes): need ~111.2 MB total
    unsigned short* xb  = (unsigned short*)(ws);                 // 32 MB bf16 x
    unsigned short* h0  = (unsigned short*)(ws + 33554432);      // 32 MB
    unsigned short* h1  = (unsigned short*)(ws + 67108864);      // 32 MB
    unsigned short* wb  = (unsigned short*)(ws + 100663296);     // 8 MB  Ws bf16
    unsigned short* wob = (unsigned short*)(ws + 109051904);     // 2 MB  Wo bf16
    float*          rsm = (float*)(ws + 111149056);              // 64 KB rowsum

    prep_kernel<<<BROWS, 256, 0, stream>>>(x, xb, rsm);
    cvt_kernel<<<(NLAYERS * DDIM * DDIM) / 1024, 256, 0, stream>>>(
        Ws, wb, NLAYERS * DDIM * DDIM);
    cvt_kernel<<<(DDIM * DDIM) / 1024, 256, 0, stream>>>(Wo, wob, DDIM * DDIM);

    dim3 g(BROWS / 128, DDIM / 128);
    gemm_bt<0><<<g, 256, 0, stream>>>(xb, wb,                 bs,            h0, nullptr, nullptr, BROWS, DDIM, DDIM);
    gemm_bt<0><<<g, 256, 0, stream>>>(h0, wb + 1 * DDIM * DDIM, bs + 1 * DDIM, h1, nullptr, nullptr, BROWS, DDIM, DDIM);
    gemm_bt<0><<<g, 256, 0, stream>>>(h1, wb + 2 * DDIM * DDIM, bs + 2 * DDIM, h0, nullptr, nullptr, BROWS, DDIM, DDIM);
    gemm_bt<1><<<g, 256, 0, stream>>>(h0, wb + 3 * DDIM * DDIM, bs + 3 * DDIM, h1, x, rsm, BROWS, DDIM, DDIM);
    gemm_bt<2><<<g, 256, 0, stream>>>(h1, wob,                bo,            out, nullptr, nullptr, BROWS, DDIM, DDIM);
}